// Round 3
// baseline (532.762 us; speedup 1.0000x reference)
//
#include <hip/hip_runtime.h>

#define NRES 384
#define CZ 128
#define NH 4
#define CH 32
#define NN (NRES * NRES)
#define NNCZ ((size_t)NN * CZ)

typedef unsigned short u16;
typedef __attribute__((ext_vector_type(4))) unsigned short us4;
typedef __attribute__((ext_vector_type(8))) unsigned short us8;
typedef __attribute__((ext_vector_type(8))) short s8;   // 8 bf16 = MFMA A/B frag
typedef __attribute__((ext_vector_type(4))) float f4;   // MFMA C/D frag

__device__ __forceinline__ float bf2f(u16 u) {
  return __uint_as_float(((unsigned)u) << 16);
}
__device__ __forceinline__ u16 f2bf(float f) {
  unsigned u = __float_as_uint(f);
  u += 0x7fffu + ((u >> 16) & 1u);  // RTNE
  return (u16)(u >> 16);
}

template<bool F32>
__device__ __forceinline__ float ld1(const void* p, size_t i) {
  if constexpr (F32) return ((const float*)p)[i];
  else return bf2f(((const u16*)p)[i]);
}

template<bool F32>
__device__ __forceinline__ void ld4v(const void* p, size_t i, float o[4]) {
  if constexpr (F32) {
    const float4 a = *(const float4*)((const float*)p + i);
    o[0] = a.x; o[1] = a.y; o[2] = a.z; o[3] = a.w;
  } else {
    const us4 v = *(const us4*)((const u16*)p + i);
    #pragma unroll
    for (int u = 0; u < 4; ++u) o[u] = bf2f(v[u]);
  }
}

template<bool F32>
__device__ __forceinline__ void ld8(const void* p, size_t i, float o[8]) {
  if constexpr (F32) {
    const float4 a = *(const float4*)((const float*)p + i);
    const float4 b = *(const float4*)((const float*)p + i + 4);
    o[0] = a.x; o[1] = a.y; o[2] = a.z; o[3] = a.w;
    o[4] = b.x; o[5] = b.y; o[6] = b.z; o[7] = b.w;
  } else {
    const us8 v = *(const us8*)((const u16*)p + i);
    #pragma unroll
    for (int u = 0; u < 8; ++u) o[u] = bf2f(v[u]);
  }
}

// ---------------------------------------------------------------------------
// Probe: decide input dtype from z's exponent-bit statistics.
// ---------------------------------------------------------------------------
__global__ void k_probe(const u16* __restrict__ z, int* __restrict__ flag) {
  int weird = 0;
  for (int i = threadIdx.x; i < 256; i += 64) {
    const int e = (z[i] >> 7) & 0xFF;
    if (e < 0x70 || e > 0x8F) weird++;
  }
  #pragma unroll
  for (int m = 1; m < 64; m <<= 1) weird += __shfl_xor(weird, m, 64);
  if (threadIdx.x == 0) *flag = (weird >= 16) ? 1 : 0;
}

// ---------------------------------------------------------------------------
// K1: LayerNorm + MFMA projections + tri_bias (transposed out).
// (unchanged)
// ---------------------------------------------------------------------------
template<bool F32>
__global__ __launch_bounds__(256, 2) void k_ln_proj(
    const void* __restrict__ z, const void* __restrict__ gma, const void* __restrict__ bta,
    const void* __restrict__ wbias, const void* __restrict__ wq, const void* __restrict__ wk,
    const void* __restrict__ wv, const void* __restrict__ wg, const void* __restrict__ bg,
    u16* __restrict__ qb, u16* __restrict__ kb, u16* __restrict__ vb, u16* __restrict__ gb,
    float* __restrict__ triT, const int* __restrict__ flag)
{
  if ((*flag != 0) != F32) return;
  __shared__ __align__(16) u16 znl[128 * 136];   // 34816 B
  __shared__ __align__(16) u16 WT[CZ * CZ];      // 32768 B, A-frag order
  const int t = threadIdx.x;
  const int lane = t & 63;
  const int wid = t >> 6;
  const int n16 = lane & 15;
  const int quad = lane >> 4;   // also LN row-group
  const int rowBase = blockIdx.x * 128;

  // ---- LayerNorm ----
  const int c0 = n16 * 8;
  float g8[8], b8[8];
  ld8<F32>(gma, c0, g8);
  ld8<F32>(bta, c0, b8);
  for (int it = 0; it < 8; ++it) {
    const int rl = wid * 32 + it * 4 + quad;
    float x[8];
    ld8<F32>(z, (size_t)(rowBase + rl) * CZ + c0, x);
    float s = 0.f, q2 = 0.f;
    #pragma unroll
    for (int u = 0; u < 8; ++u) { s += x[u]; q2 += x[u] * x[u]; }
    #pragma unroll
    for (int m = 1; m < 16; m <<= 1) {
      s  += __shfl_xor(s, m, 64);
      q2 += __shfl_xor(q2, m, 64);
    }
    const float mu = s * (1.0f / CZ);
    const float rs = rsqrtf(q2 * (1.0f / CZ) - mu * mu + 1e-5f);
    us8 o;
    #pragma unroll
    for (int u = 0; u < 8; ++u) o[u] = f2bf((x[u] - mu) * rs * g8[u] + b8[u]);
    *(us8*)&znl[rl * 136 + c0] = o;
  }
  __syncthreads();

  // ---- tri_bias (VALU; tiny). wb columns for this lane's channels in regs.
  float wb4[8][4];
  #pragma unroll
  for (int cc = 0; cc < 8; ++cc) ld4v<F32>(wbias, (size_t)(c0 + cc) * NH, wb4[cc]);
  for (int it = 0; it < 8; ++it) {
    const int rl = wid * 32 + it * 4 + quad;
    const us8 zv8 = *(const us8*)&znl[rl * 136 + c0];
    float a0 = 0.f, a1 = 0.f, a2 = 0.f, a3 = 0.f;
    #pragma unroll
    for (int cc = 0; cc < 8; ++cc) {
      const float zv = bf2f(zv8[cc]);
      a0 += zv * wb4[cc][0]; a1 += zv * wb4[cc][1];
      a2 += zv * wb4[cc][2]; a3 += zv * wb4[cc][3];
    }
    #pragma unroll
    for (int m = 1; m < 16; m <<= 1) {
      a0 += __shfl_xor(a0, m, 64); a1 += __shfl_xor(a1, m, 64);
      a2 += __shfl_xor(a2, m, 64); a3 += __shfl_xor(a3, m, 64);
    }
    if (n16 < 4) {
      const float v = (n16 == 0) ? a0 : (n16 == 1) ? a1 : (n16 == 2) ? a2 : a3;
      const int P = rowBase + rl;
      const int aI = P / NRES, bI = P % NRES;   // pair (qrow=aI, key=bI)
      triT[(size_t)n16 * NN + (size_t)bI * NRES + aI] = v;
    }
  }

  // ---- 4 projection GEMMs ----
  const u16 scl_q = 1;  // marker only
  for (int arr = 0; arr < 4; ++arr) {
    const void* W = (arr == 0) ? wq : (arr == 1) ? wk : (arr == 2) ? wv : wg;
    __syncthreads();   // prior MFMA reads of WT done
    #pragma unroll
    for (int it = 0; it < 16; ++it) {
      const int c = (t >> 5) + it * 8;
      const int m0 = (t & 31) * 4;
      float w4[4];
      ld4v<F32>(W, (size_t)c * CZ + m0, w4);
      const int ks = c >> 5, qq = (c >> 3) & 3, j = c & 7;
      #pragma unroll
      for (int mm = 0; mm < 4; ++mm) {
        const int m = m0 + mm;
        WT[ks * 4096 + (((m >> 4) * 4 + qq) * 16 + (m & 15)) * 8 + j] = f2bf(w4[mm]);
      }
    }
    __syncthreads();

    f4 acc[2][8];
    #pragma unroll
    for (int i = 0; i < 2; ++i)
      #pragma unroll
      for (int nt = 0; nt < 8; ++nt) acc[i][nt] = f4{0.f, 0.f, 0.f, 0.f};

    #pragma unroll
    for (int ks = 0; ks < 4; ++ks) {
      s8 a[2], b[8];
      #pragma unroll
      for (int i = 0; i < 2; ++i)
        a[i] = *(const s8*)&WT[ks * 4096 + (((wid * 2 + i) * 4 + quad) * 16 + n16) * 8];
      #pragma unroll
      for (int nt = 0; nt < 8; ++nt)
        b[nt] = *(const s8*)&znl[(nt * 16 + n16) * 136 + ks * 32 + quad * 8];
      #pragma unroll
      for (int i = 0; i < 2; ++i)
        #pragma unroll
        for (int nt = 0; nt < 8; ++nt)
          acc[i][nt] = __builtin_amdgcn_mfma_f32_16x16x32_bf16(a[i], b[nt], acc[i][nt], 0, 0, 0);
    }

    u16* dstb = (arr == 0) ? qb : (arr == 1) ? kb : (arr == 2) ? vb : gb;
    #pragma unroll
    for (int i = 0; i < 2; ++i) {
      const int mt = wid * 2 + i;
      const int och0 = mt * 16 + quad * 4;
      float e4[4];
      if (arr == 3) ld4v<F32>(bg, och0, e4);
      #pragma unroll
      for (int nt = 0; nt < 8; ++nt) {
        us4 o;
        #pragma unroll
        for (int r = 0; r < 4; ++r) {
          float v = acc[i][nt][r];
          if (arr == 0) v *= 0.17677669529663687f;           // CH^-0.5
          else if (arr == 3) v = 1.0f / (1.0f + __expf(-(v + e4[r])));
          o[r] = f2bf(v);
        }
        *(us4*)&dstb[(size_t)(rowBase + nt * 16 + n16) * CZ + och0] = o;
      }
    }
  }
  (void)scl_q;
}

// ---------------------------------------------------------------------------
// K2: MFMA attention, online-softmax over 4 chunks of 96 keys.
//   - K fragments read directly from global (L2-resident slice) — no KB LDS.
//   - mask bias in LDS broadcast (mbL) — frees 24 VGPRs.
//   - P written as packed bf16x2 (plain shift-or of two RTNE casts; no
//     hip_bf16.h dependency) using a key-interleave permutation applied
//     identically to V staging, so PV's k-dim order stays consistent.
//   Live state per wave-iteration: S[6] + O0/O1 + m/l — ~100 regs -> 4 w/SIMD.
//   LDS: 24576 (VB) + 5120 (Pch) + 1536 (mbL) = 31232 B.
// ---------------------------------------------------------------------------
template<bool F32>
__global__ __launch_bounds__(256, 4) void k_attn(
    const u16* __restrict__ qb, const u16* __restrict__ kb, const u16* __restrict__ vb,
    const u16* __restrict__ gb, const float* __restrict__ triT, const void* __restrict__ msk,
    u16* __restrict__ ogb, const int* __restrict__ flag)
{
  if ((*flag != 0) != F32) return;
  __shared__ __align__(16) u16 VB[12 * 4 * 32 * 8];  // [chunk32][quad][d][j], key-permuted
  __shared__ __align__(16) u16 Pch[4][16 * 40];      // per-wave P chunk
  __shared__ __align__(16) float mbL[NRES];          // mask bias per key
  const int t = threadIdx.x;
  const int i = blockIdx.x >> 2;
  const int h = blockIdx.x & 3;
  const size_t base_i = (size_t)i * NRES;

  #pragma unroll
  for (int it = 0; it < 12; ++it) {
    const int idx = t + it * 256;
    const int kk = idx >> 3;
    const int d0 = (idx & 7) * 4;
    const us4 vv = *(const us4*)&vb[(base_i + kk) * CZ + h * CH + d0];
    const int cc2 = kk >> 5;
    const int kap = kk & 31;
    const int p = 2 * (kap & 15) + (kap >> 4);   // key-interleave position
    u16* vdst = &VB[((cc2 * 4 + (p >> 3)) * 32 + d0) * 8 + (p & 7)];
    vdst[0] = vv[0]; vdst[8] = vv[1]; vdst[16] = vv[2]; vdst[24] = vv[3];
  }
  for (int idx = t; idx < NRES; idx += 256)
    mbL[idx] = 1.0e9f * (ld1<F32>(msk, base_i + idx) - 1.0f);
  __syncthreads();

  const int wid = t >> 6;
  const int lane = t & 63;
  const int n = lane & 15;
  const int quad = lane >> 4;
  const float* trih = triT + (size_t)h * NN;
  u16* pb = &Pch[wid][0];

  for (int jt = wid; jt < 24; jt += 4) {
    const int jrow0 = jt * 16;
    const s8 aq = *(const s8*)&qb[(base_i + jrow0 + n) * CZ + h * CH + quad * 8];

    f4 O0 = {0.f, 0.f, 0.f, 0.f}, O1 = {0.f, 0.f, 0.f, 0.f};
    f4 l4 = {0.f, 0.f, 0.f, 0.f};
    f4 m4 = {-1.0e30f, -1.0e30f, -1.0e30f, -1.0e30f};

    #pragma unroll 1
    for (int cc = 0; cc < 4; ++cc) {
      // ---- QK^T for 6 key tiles (96 keys), K straight from L2 ----
      f4 S[6];
      #pragma unroll
      for (int u = 0; u < 6; ++u) {
        const int tt = cc * 6 + u;
        const s8 bk = *(const s8*)&kb[(base_i + tt * 16 + n) * CZ + h * CH + quad * 8];
        const f4 z4 = {0.f, 0.f, 0.f, 0.f};
        S[u] = __builtin_amdgcn_mfma_f32_16x16x32_bf16(aq, bk, z4, 0, 0, 0);
      }
      // ---- bias: tri (f32 float4) + mask (LDS broadcast) ----
      #pragma unroll
      for (int u = 0; u < 6; ++u) {
        const int tt = cc * 6 + u;
        const float mbv = mbL[tt * 16 + n];
        const float4 t4 = *(const float4*)&trih[(size_t)(tt * 16 + n) * NRES + jrow0 + quad * 4];
        S[u][0] += t4.x + mbv;
        S[u][1] += t4.y + mbv;
        S[u][2] += t4.z + mbv;
        S[u][3] += t4.w + mbv;
      }
      // ---- online softmax: chunk max, rescale running state ----
      f4 mx = S[0];
      #pragma unroll
      for (int u = 1; u < 6; ++u) {
        #pragma unroll
        for (int r = 0; r < 4; ++r) mx[r] = fmaxf(mx[r], S[u][r]);
      }
      #pragma unroll
      for (int sft = 1; sft < 16; sft <<= 1) {
        #pragma unroll
        for (int r = 0; r < 4; ++r) mx[r] = fmaxf(mx[r], __shfl_xor(mx[r], sft, 64));
      }
      f4 sc;
      #pragma unroll
      for (int r = 0; r < 4; ++r) {
        const float mn = fmaxf(m4[r], mx[r]);
        sc[r] = __expf(m4[r] - mn);
        m4[r] = mn;
      }
      #pragma unroll
      for (int r = 0; r < 4; ++r) {
        O0[r] *= sc[r]; O1[r] *= sc[r]; l4[r] *= sc[r];
      }
      #pragma unroll
      for (int u = 0; u < 6; ++u) {
        #pragma unroll
        for (int r = 0; r < 4; ++r) {
          S[u][r] = __expf(S[u][r] - m4[r]);
          l4[r] += S[u][r];
        }
      }
      // ---- P pack (bf16x2 shift-or) -> LDS -> PV, 3 sub-chunks of 32 keys ----
      #pragma unroll
      for (int s = 0; s < 3; ++s) {
        #pragma unroll
        for (int r = 0; r < 4; ++r) {
          const unsigned w = (unsigned)f2bf(S[2 * s][r]) |
                             ((unsigned)f2bf(S[2 * s + 1][r]) << 16);
          *(unsigned*)&pb[(quad * 4 + r) * 40 + n * 2] = w;
        }
        const int C = cc * 3 + s;
        const s8 ap  = *(const s8*)&pb[n * 40 + quad * 8];
        const s8 bv0 = *(const s8*)&VB[((C * 4 + quad) * 32 + n) * 8];
        const s8 bv1 = *(const s8*)&VB[((C * 4 + quad) * 32 + 16 + n) * 8];
        O0 = __builtin_amdgcn_mfma_f32_16x16x32_bf16(ap, bv0, O0, 0, 0, 0);
        O1 = __builtin_amdgcn_mfma_f32_16x16x32_bf16(ap, bv1, O1, 0, 0, 0);
      }
    }

    // ---- finish: sum-reduce over the 16-lane key axis, gate, store ----
    f4 sum = l4;
    #pragma unroll
    for (int sft = 1; sft < 16; sft <<= 1) {
      #pragma unroll
      for (int r = 0; r < 4; ++r) sum[r] += __shfl_xor(sum[r], sft, 64);
    }
    f4 inv;
    #pragma unroll
    for (int r = 0; r < 4; ++r) inv[r] = 1.0f / sum[r];

    #pragma unroll
    for (int r = 0; r < 4; ++r) {
      const size_t rowoff = (base_i + jrow0 + quad * 4 + r) * CZ + h * CH;
      const float iv = inv[r];
      const float g0 = bf2f(gb[rowoff + n]);
      const float g1 = bf2f(gb[rowoff + 16 + n]);
      ogb[rowoff + n]      = f2bf(O0[r] * iv * g0);
      ogb[rowoff + 16 + n] = f2bf(O1[r] * iv * g1);
    }
  }
}

// ---------------------------------------------------------------------------
// K3: out = (o*g) @ w_o + b_o — same MFMA structure as one k_ln_proj weight.
// (unchanged)
// ---------------------------------------------------------------------------
template<bool F32>
__global__ __launch_bounds__(256, 2) void k_out(
    const u16* __restrict__ og, const void* __restrict__ wo, const void* __restrict__ bo,
    void* __restrict__ outp, const int* __restrict__ flag)
{
  if ((*flag != 0) != F32) return;
  __shared__ __align__(16) u16 ol[128 * 136];
  __shared__ __align__(16) u16 WT[CZ * CZ];
  const int t = threadIdx.x;
  const int lane = t & 63;
  const int wid = t >> 6;
  const int n16 = lane & 15;
  const int quad = lane >> 4;
  const int rowBase = blockIdx.x * 128;

  #pragma unroll
  for (int it = 0; it < 8; ++it) {
    const int idx8 = t + it * 256;
    const int r = idx8 >> 4;
    const int c0 = (idx8 & 15) * 8;
    *(us8*)&ol[r * 136 + c0] = *(const us8*)&og[(size_t)(rowBase + r) * CZ + c0];
  }
  #pragma unroll
  for (int it = 0; it < 16; ++it) {
    const int c = (t >> 5) + it * 8;
    const int m0 = (t & 31) * 4;
    float w4[4];
    ld4v<F32>(wo, (size_t)c * CZ + m0, w4);
    const int ks = c >> 5, qq = (c >> 3) & 3, j = c & 7;
    #pragma unroll
    for (int mm = 0; mm < 4; ++mm) {
      const int m = m0 + mm;
      WT[ks * 4096 + (((m >> 4) * 4 + qq) * 16 + (m & 15)) * 8 + j] = f2bf(w4[mm]);
    }
  }
  __syncthreads();

  f4 acc[2][8];
  #pragma unroll
  for (int i = 0; i < 2; ++i)
    #pragma unroll
    for (int nt = 0; nt < 8; ++nt) acc[i][nt] = f4{0.f, 0.f, 0.f, 0.f};

  #pragma unroll
  for (int ks = 0; ks < 4; ++ks) {
    s8 a[2], b[8];
    #pragma unroll
    for (int i = 0; i < 2; ++i)
      a[i] = *(const s8*)&WT[ks * 4096 + (((wid * 2 + i) * 4 + quad) * 16 + n16) * 8];
    #pragma unroll
    for (int nt = 0; nt < 8; ++nt)
      b[nt] = *(const s8*)&ol[(nt * 16 + n16) * 136 + ks * 32 + quad * 8];
    #pragma unroll
    for (int i = 0; i < 2; ++i)
      #pragma unroll
      for (int nt = 0; nt < 8; ++nt)
        acc[i][nt] = __builtin_amdgcn_mfma_f32_16x16x32_bf16(a[i], b[nt], acc[i][nt], 0, 0, 0);
  }

  #pragma unroll
  for (int i = 0; i < 2; ++i) {
    const int och0 = (wid * 2 + i) * 16 + quad * 4;
    float b4[4];
    ld4v<F32>(bo, och0, b4);
    #pragma unroll
    for (int nt = 0; nt < 8; ++nt) {
      const size_t off = (size_t)(rowBase + nt * 16 + n16) * CZ + och0;
      if constexpr (F32) {
        float4 o;
        o.x = acc[i][nt][0] + b4[0]; o.y = acc[i][nt][1] + b4[1];
        o.z = acc[i][nt][2] + b4[2]; o.w = acc[i][nt][3] + b4[3];
        *(float4*)&((float*)outp)[off] = o;
      } else {
        us4 o;
        #pragma unroll
        for (int r = 0; r < 4; ++r) o[r] = f2bf(acc[i][nt][r] + b4[r]);
        *(us4*)&((u16*)outp)[off] = o;
      }
    }
  }
}

extern "C" void kernel_launch(void* const* d_in, const int* in_sizes, int n_in,
                              void* d_out, int out_size, void* d_ws, size_t ws_size,
                              hipStream_t stream) {
  const void* z     = d_in[0];
  const void* msk   = d_in[1];
  const void* gma   = d_in[2];
  const void* bta   = d_in[3];
  const void* wbias = d_in[4];
  const void* wq    = d_in[5];
  const void* wk    = d_in[6];
  const void* wv    = d_in[7];
  const void* wg    = d_in[8];
  const void* bg    = d_in[9];
  const void* wo    = d_in[10];
  const void* bo    = d_in[11];

  char* ws = (char*)d_ws;
  int* flag = (int*)ws;
  u16* qb = (u16*)(ws + 256);
  u16* kb = qb + NNCZ;
  u16* vb = kb + NNCZ;
  u16* gb = vb + NNCZ;
  float* triT = (float*)(gb + NNCZ);
  u16* ogb = qb;  // alias: q slice consumed by the same wave-iteration that writes o

  k_probe<<<dim3(1), dim3(64), 0, stream>>>((const u16*)z, flag);

  k_ln_proj<false><<<dim3(NN / 128), dim3(256), 0, stream>>>(
      z, gma, bta, wbias, wq, wk, wv, wg, bg, qb, kb, vb, gb, triT, flag);
  k_ln_proj<true><<<dim3(NN / 128), dim3(256), 0, stream>>>(
      z, gma, bta, wbias, wq, wk, wv, wg, bg, qb, kb, vb, gb, triT, flag);

  k_attn<false><<<dim3(NRES * NH), dim3(256), 0, stream>>>(
      qb, kb, vb, gb, triT, msk, ogb, flag);
  k_attn<true><<<dim3(NRES * NH), dim3(256), 0, stream>>>(
      qb, kb, vb, gb, triT, msk, ogb, flag);

  k_out<false><<<dim3(NN / 128), dim3(256), 0, stream>>>(ogb, wo, bo, d_out, flag);
  k_out<true><<<dim3(NN / 128), dim3(256), 0, stream>>>(ogb, wo, bo, d_out, flag);
}

// Round 4
// 500.137 us; speedup vs baseline: 1.0652x; 1.0652x over previous
//
#include <hip/hip_runtime.h>

#define NRES 384
#define CZ 128
#define NH 4
#define CH 32
#define NN (NRES * NRES)
#define NNCZ ((size_t)NN * CZ)

typedef unsigned short u16;
typedef __attribute__((ext_vector_type(4))) unsigned short us4;
typedef __attribute__((ext_vector_type(8))) unsigned short us8;
typedef __attribute__((ext_vector_type(8))) short s8;   // 8 bf16 = MFMA A/B frag
typedef __attribute__((ext_vector_type(4))) float f4;   // MFMA C/D frag

__device__ __forceinline__ float bf2f(u16 u) {
  return __uint_as_float(((unsigned)u) << 16);
}
__device__ __forceinline__ u16 f2bf(float f) {
  unsigned u = __float_as_uint(f);
  u += 0x7fffu + ((u >> 16) & 1u);  // RTNE
  return (u16)(u >> 16);
}

template<bool F32>
__device__ __forceinline__ float ld1(const void* p, size_t i) {
  if constexpr (F32) return ((const float*)p)[i];
  else return bf2f(((const u16*)p)[i]);
}

template<bool F32>
__device__ __forceinline__ void ld4v(const void* p, size_t i, float o[4]) {
  if constexpr (F32) {
    const float4 a = *(const float4*)((const float*)p + i);
    o[0] = a.x; o[1] = a.y; o[2] = a.z; o[3] = a.w;
  } else {
    const us4 v = *(const us4*)((const u16*)p + i);
    #pragma unroll
    for (int u = 0; u < 4; ++u) o[u] = bf2f(v[u]);
  }
}

template<bool F32>
__device__ __forceinline__ void ld8(const void* p, size_t i, float o[8]) {
  if constexpr (F32) {
    const float4 a = *(const float4*)((const float*)p + i);
    const float4 b = *(const float4*)((const float*)p + i + 4);
    o[0] = a.x; o[1] = a.y; o[2] = a.z; o[3] = a.w;
    o[4] = b.x; o[5] = b.y; o[6] = b.z; o[7] = b.w;
  } else {
    const us8 v = *(const us8*)((const u16*)p + i);
    #pragma unroll
    for (int u = 0; u < 8; ++u) o[u] = bf2f(v[u]);
  }
}

// ---------------------------------------------------------------------------
// Probe: decide input dtype from z's exponent-bit statistics.
// ---------------------------------------------------------------------------
__global__ void k_probe(const u16* __restrict__ z, int* __restrict__ flag) {
  int weird = 0;
  for (int i = threadIdx.x; i < 256; i += 64) {
    const int e = (z[i] >> 7) & 0xFF;
    if (e < 0x70 || e > 0x8F) weird++;
  }
  #pragma unroll
  for (int m = 1; m < 64; m <<= 1) weird += __shfl_xor(weird, m, 64);
  if (threadIdx.x == 0) *flag = (weird >= 16) ? 1 : 0;
}

// ---------------------------------------------------------------------------
// K1: LayerNorm + MFMA projections + tri_bias (transposed out).
// (unchanged)
// ---------------------------------------------------------------------------
template<bool F32>
__global__ __launch_bounds__(256, 2) void k_ln_proj(
    const void* __restrict__ z, const void* __restrict__ gma, const void* __restrict__ bta,
    const void* __restrict__ wbias, const void* __restrict__ wq, const void* __restrict__ wk,
    const void* __restrict__ wv, const void* __restrict__ wg, const void* __restrict__ bg,
    u16* __restrict__ qb, u16* __restrict__ kb, u16* __restrict__ vb, u16* __restrict__ gb,
    float* __restrict__ triT, const int* __restrict__ flag)
{
  if ((*flag != 0) != F32) return;
  __shared__ __align__(16) u16 znl[128 * 136];   // 34816 B
  __shared__ __align__(16) u16 WT[CZ * CZ];      // 32768 B, A-frag order
  const int t = threadIdx.x;
  const int lane = t & 63;
  const int wid = t >> 6;
  const int n16 = lane & 15;
  const int quad = lane >> 4;   // also LN row-group
  const int rowBase = blockIdx.x * 128;

  // ---- LayerNorm ----
  const int c0 = n16 * 8;
  float g8[8], b8[8];
  ld8<F32>(gma, c0, g8);
  ld8<F32>(bta, c0, b8);
  for (int it = 0; it < 8; ++it) {
    const int rl = wid * 32 + it * 4 + quad;
    float x[8];
    ld8<F32>(z, (size_t)(rowBase + rl) * CZ + c0, x);
    float s = 0.f, q2 = 0.f;
    #pragma unroll
    for (int u = 0; u < 8; ++u) { s += x[u]; q2 += x[u] * x[u]; }
    #pragma unroll
    for (int m = 1; m < 16; m <<= 1) {
      s  += __shfl_xor(s, m, 64);
      q2 += __shfl_xor(q2, m, 64);
    }
    const float mu = s * (1.0f / CZ);
    const float rs = rsqrtf(q2 * (1.0f / CZ) - mu * mu + 1e-5f);
    us8 o;
    #pragma unroll
    for (int u = 0; u < 8; ++u) o[u] = f2bf((x[u] - mu) * rs * g8[u] + b8[u]);
    *(us8*)&znl[rl * 136 + c0] = o;
  }
  __syncthreads();

  // ---- tri_bias (VALU; tiny). wb columns for this lane's channels in regs.
  float wb4[8][4];
  #pragma unroll
  for (int cc = 0; cc < 8; ++cc) ld4v<F32>(wbias, (size_t)(c0 + cc) * NH, wb4[cc]);
  for (int it = 0; it < 8; ++it) {
    const int rl = wid * 32 + it * 4 + quad;
    const us8 zv8 = *(const us8*)&znl[rl * 136 + c0];
    float a0 = 0.f, a1 = 0.f, a2 = 0.f, a3 = 0.f;
    #pragma unroll
    for (int cc = 0; cc < 8; ++cc) {
      const float zv = bf2f(zv8[cc]);
      a0 += zv * wb4[cc][0]; a1 += zv * wb4[cc][1];
      a2 += zv * wb4[cc][2]; a3 += zv * wb4[cc][3];
    }
    #pragma unroll
    for (int m = 1; m < 16; m <<= 1) {
      a0 += __shfl_xor(a0, m, 64); a1 += __shfl_xor(a1, m, 64);
      a2 += __shfl_xor(a2, m, 64); a3 += __shfl_xor(a3, m, 64);
    }
    if (n16 < 4) {
      const float v = (n16 == 0) ? a0 : (n16 == 1) ? a1 : (n16 == 2) ? a2 : a3;
      const int P = rowBase + rl;
      const int aI = P / NRES, bI = P % NRES;   // pair (qrow=aI, key=bI)
      triT[(size_t)n16 * NN + (size_t)bI * NRES + aI] = v;
    }
  }

  // ---- 4 projection GEMMs ----
  const u16 scl_q = 1;  // marker only
  for (int arr = 0; arr < 4; ++arr) {
    const void* W = (arr == 0) ? wq : (arr == 1) ? wk : (arr == 2) ? wv : wg;
    __syncthreads();   // prior MFMA reads of WT done
    #pragma unroll
    for (int it = 0; it < 16; ++it) {
      const int c = (t >> 5) + it * 8;
      const int m0 = (t & 31) * 4;
      float w4[4];
      ld4v<F32>(W, (size_t)c * CZ + m0, w4);
      const int ks = c >> 5, qq = (c >> 3) & 3, j = c & 7;
      #pragma unroll
      for (int mm = 0; mm < 4; ++mm) {
        const int m = m0 + mm;
        WT[ks * 4096 + (((m >> 4) * 4 + qq) * 16 + (m & 15)) * 8 + j] = f2bf(w4[mm]);
      }
    }
    __syncthreads();

    f4 acc[2][8];
    #pragma unroll
    for (int i = 0; i < 2; ++i)
      #pragma unroll
      for (int nt = 0; nt < 8; ++nt) acc[i][nt] = f4{0.f, 0.f, 0.f, 0.f};

    #pragma unroll
    for (int ks = 0; ks < 4; ++ks) {
      s8 a[2], b[8];
      #pragma unroll
      for (int i = 0; i < 2; ++i)
        a[i] = *(const s8*)&WT[ks * 4096 + (((wid * 2 + i) * 4 + quad) * 16 + n16) * 8];
      #pragma unroll
      for (int nt = 0; nt < 8; ++nt)
        b[nt] = *(const s8*)&znl[(nt * 16 + n16) * 136 + ks * 32 + quad * 8];
      #pragma unroll
      for (int i = 0; i < 2; ++i)
        #pragma unroll
        for (int nt = 0; nt < 8; ++nt)
          acc[i][nt] = __builtin_amdgcn_mfma_f32_16x16x32_bf16(a[i], b[nt], acc[i][nt], 0, 0, 0);
    }

    u16* dstb = (arr == 0) ? qb : (arr == 1) ? kb : (arr == 2) ? vb : gb;
    #pragma unroll
    for (int i = 0; i < 2; ++i) {
      const int mt = wid * 2 + i;
      const int och0 = mt * 16 + quad * 4;
      float e4[4];
      if (arr == 3) ld4v<F32>(bg, och0, e4);
      #pragma unroll
      for (int nt = 0; nt < 8; ++nt) {
        us4 o;
        #pragma unroll
        for (int r = 0; r < 4; ++r) {
          float v = acc[i][nt][r];
          if (arr == 0) v *= 0.17677669529663687f;           // CH^-0.5
          else if (arr == 3) v = 1.0f / (1.0f + __expf(-(v + e4[r])));
          o[r] = f2bf(v);
        }
        *(us4*)&dstb[(size_t)(rowBase + nt * 16 + n16) * CZ + och0] = o;
      }
    }
  }
  (void)scl_q;
}

// ---------------------------------------------------------------------------
// K2: MFMA attention, online softmax, 2 q-tiles per wave (register tiling).
//   - 64-key chunks (4 key-tiles): S = 2x4 f4 keeps regs ~140.
//   - each K/V fragment feeds 2 MFMAs (q-tiles jrowA, jrowA+16) -> K global
//     traffic halves vs R3 (L2 pressure halves, HBM spill drops).
//   - K chunk cc+1 prefetched into regs during chunk cc softmax+PV (latency
//     hidden under ~300cy of VALU).
//   - tri loads for the pair hit the same 128B line.
//   LDS: 24576 (VB) + 10240 (Pch[4][2]) + 1536 (mbL) = 36352 B -> 4 blk/CU.
// ---------------------------------------------------------------------------
template<bool F32>
__global__ __launch_bounds__(256, 3) void k_attn(
    const u16* __restrict__ qb, const u16* __restrict__ kb, const u16* __restrict__ vb,
    const u16* __restrict__ gb, const float* __restrict__ triT, const void* __restrict__ msk,
    u16* __restrict__ ogb, const int* __restrict__ flag)
{
  if ((*flag != 0) != F32) return;
  __shared__ __align__(16) u16 VB[12 * 4 * 32 * 8];  // [sub32][quad][d][j], key-permuted
  __shared__ __align__(16) u16 Pch[4][2][16 * 40];   // per-wave, per-qtile P chunk
  __shared__ __align__(16) float mbL[NRES];          // mask bias per key
  const int t = threadIdx.x;
  const int i = blockIdx.x >> 2;
  const int h = blockIdx.x & 3;
  const size_t base_i = (size_t)i * NRES;

  #pragma unroll
  for (int it = 0; it < 12; ++it) {
    const int idx = t + it * 256;
    const int kk = idx >> 3;
    const int d0 = (idx & 7) * 4;
    const us4 vv = *(const us4*)&vb[(base_i + kk) * CZ + h * CH + d0];
    const int cc2 = kk >> 5;
    const int kap = kk & 31;
    const int p = 2 * (kap & 15) + (kap >> 4);   // key-interleave position
    u16* vdst = &VB[((cc2 * 4 + (p >> 3)) * 32 + d0) * 8 + (p & 7)];
    vdst[0] = vv[0]; vdst[8] = vv[1]; vdst[16] = vv[2]; vdst[24] = vv[3];
  }
  for (int idx = t; idx < NRES; idx += 256)
    mbL[idx] = 1.0e9f * (ld1<F32>(msk, base_i + idx) - 1.0f);
  __syncthreads();

  const int wid = t >> 6;
  const int lane = t & 63;
  const int n = lane & 15;
  const int quad = lane >> 4;
  const float* trih = triT + (size_t)h * NN;
  u16* pbA = &Pch[wid][0][0];
  u16* pbB = &Pch[wid][1][0];

  for (int pr = wid; pr < 12; pr += 4) {
    const int jrowA = pr * 32;
    const int jrowB = jrowA + 16;
    const s8 aqA = *(const s8*)&qb[(base_i + jrowA + n) * CZ + h * CH + quad * 8];
    const s8 aqB = *(const s8*)&qb[(base_i + jrowB + n) * CZ + h * CH + quad * 8];

    f4 O0A = {0.f,0.f,0.f,0.f}, O1A = {0.f,0.f,0.f,0.f};
    f4 O0B = {0.f,0.f,0.f,0.f}, O1B = {0.f,0.f,0.f,0.f};
    f4 lA = {0.f,0.f,0.f,0.f}, lB = {0.f,0.f,0.f,0.f};
    f4 mA = {-1.0e30f,-1.0e30f,-1.0e30f,-1.0e30f};
    f4 mB = {-1.0e30f,-1.0e30f,-1.0e30f,-1.0e30f};

    // preload K chunk 0
    s8 bk[4];
    #pragma unroll
    for (int u = 0; u < 4; ++u)
      bk[u] = *(const s8*)&kb[(base_i + u * 16 + n) * CZ + h * CH + quad * 8];

    #pragma unroll 1
    for (int cc = 0; cc < 6; ++cc) {
      // ---- QK^T for 4 key tiles (64 keys), both q-tiles ----
      f4 SA[4], SB[4];
      #pragma unroll
      for (int u = 0; u < 4; ++u) {
        const f4 z4 = {0.f, 0.f, 0.f, 0.f};
        SA[u] = __builtin_amdgcn_mfma_f32_16x16x32_bf16(aqA, bk[u], z4, 0, 0, 0);
        SB[u] = __builtin_amdgcn_mfma_f32_16x16x32_bf16(aqB, bk[u], z4, 0, 0, 0);
      }
      // ---- prefetch next chunk's K (hidden under softmax+PV) ----
      if (cc < 5) {
        #pragma unroll
        for (int u = 0; u < 4; ++u)
          bk[u] = *(const s8*)&kb[(base_i + ((cc + 1) * 4 + u) * 16 + n) * CZ + h * CH + quad * 8];
      }
      // ---- bias: tri (f32 float4, paired lines) + mask (LDS broadcast) ----
      #pragma unroll
      for (int u = 0; u < 4; ++u) {
        const int tt = cc * 4 + u;
        const float mbv = mbL[tt * 16 + n];
        const size_t trow = (size_t)(tt * 16 + n) * NRES;
        const float4 tA = *(const float4*)&trih[trow + jrowA + quad * 4];
        const float4 tB = *(const float4*)&trih[trow + jrowB + quad * 4];
        SA[u][0] += tA.x + mbv; SA[u][1] += tA.y + mbv;
        SA[u][2] += tA.z + mbv; SA[u][3] += tA.w + mbv;
        SB[u][0] += tB.x + mbv; SB[u][1] += tB.y + mbv;
        SB[u][2] += tB.z + mbv; SB[u][3] += tB.w + mbv;
      }
      // ---- online softmax: chunk max, rescale running state ----
      f4 mxA = SA[0], mxB = SB[0];
      #pragma unroll
      for (int u = 1; u < 4; ++u) {
        #pragma unroll
        for (int r = 0; r < 4; ++r) {
          mxA[r] = fmaxf(mxA[r], SA[u][r]);
          mxB[r] = fmaxf(mxB[r], SB[u][r]);
        }
      }
      #pragma unroll
      for (int sft = 1; sft < 16; sft <<= 1) {
        #pragma unroll
        for (int r = 0; r < 4; ++r) {
          mxA[r] = fmaxf(mxA[r], __shfl_xor(mxA[r], sft, 64));
          mxB[r] = fmaxf(mxB[r], __shfl_xor(mxB[r], sft, 64));
        }
      }
      #pragma unroll
      for (int r = 0; r < 4; ++r) {
        const float mnA = fmaxf(mA[r], mxA[r]);
        const float scA = __expf(mA[r] - mnA);
        mA[r] = mnA;
        O0A[r] *= scA; O1A[r] *= scA; lA[r] *= scA;
        const float mnB = fmaxf(mB[r], mxB[r]);
        const float scB = __expf(mB[r] - mnB);
        mB[r] = mnB;
        O0B[r] *= scB; O1B[r] *= scB; lB[r] *= scB;
      }
      #pragma unroll
      for (int u = 0; u < 4; ++u) {
        #pragma unroll
        for (int r = 0; r < 4; ++r) {
          SA[u][r] = __expf(SA[u][r] - mA[r]);
          lA[r] += SA[u][r];
          SB[u][r] = __expf(SB[u][r] - mB[r]);
          lB[r] += SB[u][r];
        }
      }
      // ---- P pack -> LDS -> PV, 2 sub-chunks of 32 keys; V frags shared ----
      #pragma unroll
      for (int s = 0; s < 2; ++s) {
        #pragma unroll
        for (int r = 0; r < 4; ++r) {
          const unsigned wA = (unsigned)f2bf(SA[2 * s][r]) |
                              ((unsigned)f2bf(SA[2 * s + 1][r]) << 16);
          *(unsigned*)&pbA[(quad * 4 + r) * 40 + n * 2] = wA;
          const unsigned wB = (unsigned)f2bf(SB[2 * s][r]) |
                              ((unsigned)f2bf(SB[2 * s + 1][r]) << 16);
          *(unsigned*)&pbB[(quad * 4 + r) * 40 + n * 2] = wB;
        }
        const int C = cc * 2 + s;
        const s8 apA = *(const s8*)&pbA[n * 40 + quad * 8];
        const s8 apB = *(const s8*)&pbB[n * 40 + quad * 8];
        const s8 bv0 = *(const s8*)&VB[((C * 4 + quad) * 32 + n) * 8];
        const s8 bv1 = *(const s8*)&VB[((C * 4 + quad) * 32 + 16 + n) * 8];
        O0A = __builtin_amdgcn_mfma_f32_16x16x32_bf16(apA, bv0, O0A, 0, 0, 0);
        O1A = __builtin_amdgcn_mfma_f32_16x16x32_bf16(apA, bv1, O1A, 0, 0, 0);
        O0B = __builtin_amdgcn_mfma_f32_16x16x32_bf16(apB, bv0, O0B, 0, 0, 0);
        O1B = __builtin_amdgcn_mfma_f32_16x16x32_bf16(apB, bv1, O1B, 0, 0, 0);
      }
    }

    // ---- finish: sum-reduce over the 16-lane key axis, gate, store ----
    f4 sA = lA, sB = lB;
    #pragma unroll
    for (int sft = 1; sft < 16; sft <<= 1) {
      #pragma unroll
      for (int r = 0; r < 4; ++r) {
        sA[r] += __shfl_xor(sA[r], sft, 64);
        sB[r] += __shfl_xor(sB[r], sft, 64);
      }
    }
    #pragma unroll
    for (int r = 0; r < 4; ++r) {
      const float ivA = 1.0f / sA[r];
      const size_t rowA = (base_i + jrowA + quad * 4 + r) * CZ + h * CH;
      const float gA0 = bf2f(gb[rowA + n]);
      const float gA1 = bf2f(gb[rowA + 16 + n]);
      ogb[rowA + n]      = f2bf(O0A[r] * ivA * gA0);
      ogb[rowA + 16 + n] = f2bf(O1A[r] * ivA * gA1);
      const float ivB = 1.0f / sB[r];
      const size_t rowB = (base_i + jrowB + quad * 4 + r) * CZ + h * CH;
      const float gB0 = bf2f(gb[rowB + n]);
      const float gB1 = bf2f(gb[rowB + 16 + n]);
      ogb[rowB + n]      = f2bf(O0B[r] * ivB * gB0);
      ogb[rowB + 16 + n] = f2bf(O1B[r] * ivB * gB1);
    }
  }
}

// ---------------------------------------------------------------------------
// K3: out = (o*g) @ w_o + b_o — same MFMA structure as one k_ln_proj weight.
// (unchanged)
// ---------------------------------------------------------------------------
template<bool F32>
__global__ __launch_bounds__(256, 2) void k_out(
    const u16* __restrict__ og, const void* __restrict__ wo, const void* __restrict__ bo,
    void* __restrict__ outp, const int* __restrict__ flag)
{
  if ((*flag != 0) != F32) return;
  __shared__ __align__(16) u16 ol[128 * 136];
  __shared__ __align__(16) u16 WT[CZ * CZ];
  const int t = threadIdx.x;
  const int lane = t & 63;
  const int wid = t >> 6;
  const int n16 = lane & 15;
  const int quad = lane >> 4;
  const int rowBase = blockIdx.x * 128;

  #pragma unroll
  for (int it = 0; it < 8; ++it) {
    const int idx8 = t + it * 256;
    const int r = idx8 >> 4;
    const int c0 = (idx8 & 15) * 8;
    *(us8*)&ol[r * 136 + c0] = *(const us8*)&og[(size_t)(rowBase + r) * CZ + c0];
  }
  #pragma unroll
  for (int it = 0; it < 16; ++it) {
    const int c = (t >> 5) + it * 8;
    const int m0 = (t & 31) * 4;
    float w4[4];
    ld4v<F32>(wo, (size_t)c * CZ + m0, w4);
    const int ks = c >> 5, qq = (c >> 3) & 3, j = c & 7;
    #pragma unroll
    for (int mm = 0; mm < 4; ++mm) {
      const int m = m0 + mm;
      WT[ks * 4096 + (((m >> 4) * 4 + qq) * 16 + (m & 15)) * 8 + j] = f2bf(w4[mm]);
    }
  }
  __syncthreads();

  f4 acc[2][8];
  #pragma unroll
  for (int i = 0; i < 2; ++i)
    #pragma unroll
    for (int nt = 0; nt < 8; ++nt) acc[i][nt] = f4{0.f, 0.f, 0.f, 0.f};

  #pragma unroll
  for (int ks = 0; ks < 4; ++ks) {
    s8 a[2], b[8];
    #pragma unroll
    for (int i = 0; i < 2; ++i)
      a[i] = *(const s8*)&WT[ks * 4096 + (((wid * 2 + i) * 4 + quad) * 16 + n16) * 8];
    #pragma unroll
    for (int nt = 0; nt < 8; ++nt)
      b[nt] = *(const s8*)&ol[(nt * 16 + n16) * 136 + ks * 32 + quad * 8];
    #pragma unroll
    for (int i = 0; i < 2; ++i)
      #pragma unroll
      for (int nt = 0; nt < 8; ++nt)
        acc[i][nt] = __builtin_amdgcn_mfma_f32_16x16x32_bf16(a[i], b[nt], acc[i][nt], 0, 0, 0);
  }

  #pragma unroll
  for (int i = 0; i < 2; ++i) {
    const int och0 = (wid * 2 + i) * 16 + quad * 4;
    float b4[4];
    ld4v<F32>(bo, och0, b4);
    #pragma unroll
    for (int nt = 0; nt < 8; ++nt) {
      const size_t off = (size_t)(rowBase + nt * 16 + n16) * CZ + och0;
      if constexpr (F32) {
        float4 o;
        o.x = acc[i][nt][0] + b4[0]; o.y = acc[i][nt][1] + b4[1];
        o.z = acc[i][nt][2] + b4[2]; o.w = acc[i][nt][3] + b4[3];
        *(float4*)&((float*)outp)[off] = o;
      } else {
        us4 o;
        #pragma unroll
        for (int r = 0; r < 4; ++r) o[r] = f2bf(acc[i][nt][r] + b4[r]);
        *(us4*)&((u16*)outp)[off] = o;
      }
    }
  }
}

extern "C" void kernel_launch(void* const* d_in, const int* in_sizes, int n_in,
                              void* d_out, int out_size, void* d_ws, size_t ws_size,
                              hipStream_t stream) {
  const void* z     = d_in[0];
  const void* msk   = d_in[1];
  const void* gma   = d_in[2];
  const void* bta   = d_in[3];
  const void* wbias = d_in[4];
  const void* wq    = d_in[5];
  const void* wk    = d_in[6];
  const void* wv    = d_in[7];
  const void* wg    = d_in[8];
  const void* bg    = d_in[9];
  const void* wo    = d_in[10];
  const void* bo    = d_in[11];

  char* ws = (char*)d_ws;
  int* flag = (int*)ws;
  u16* qb = (u16*)(ws + 256);
  u16* kb = qb + NNCZ;
  u16* vb = kb + NNCZ;
  u16* gb = vb + NNCZ;
  float* triT = (float*)(gb + NNCZ);
  u16* ogb = qb;  // alias: q slice consumed by the same wave-iteration that writes o

  k_probe<<<dim3(1), dim3(64), 0, stream>>>((const u16*)z, flag);

  k_ln_proj<false><<<dim3(NN / 128), dim3(256), 0, stream>>>(
      z, gma, bta, wbias, wq, wk, wv, wg, bg, qb, kb, vb, gb, triT, flag);
  k_ln_proj<true><<<dim3(NN / 128), dim3(256), 0, stream>>>(
      z, gma, bta, wbias, wq, wk, wv, wg, bg, qb, kb, vb, gb, triT, flag);

  k_attn<false><<<dim3(NRES * NH), dim3(256), 0, stream>>>(
      qb, kb, vb, gb, triT, msk, ogb, flag);
  k_attn<true><<<dim3(NRES * NH), dim3(256), 0, stream>>>(
      qb, kb, vb, gb, triT, msk, ogb, flag);

  k_out<false><<<dim3(NN / 128), dim3(256), 0, stream>>>(ogb, wo, bo, d_out, flag);
  k_out<true><<<dim3(NN / 128), dim3(256), 0, stream>>>(ogb, wo, bo, d_out, flag);
}